// Round 5
// baseline (1128.728 us; speedup 1.0000x reference)
//
#include <hip/hip_runtime.h>
#include <stdint.h>

#define N_ROWS 262144
#define D_DIM  1024
#define H_DIM  512
#define N_SEG  512

typedef __attribute__((ext_vector_type(4)))  float  f32x4;
typedef __attribute__((ext_vector_type(16))) float  f32x16;
typedef __attribute__((ext_vector_type(8)))  __bf16 bf16x8;
typedef __attribute__((ext_vector_type(4)))  unsigned short u16x4;
typedef __attribute__((ext_vector_type(8)))  unsigned short u16x8;

static __device__ __forceinline__ unsigned short f2bf(float f) {
  union { float f; uint32_t u; } c; c.f = f;
  return (unsigned short)((c.u + 0x7FFFu + ((c.u >> 16) & 1u)) >> 16);  // RNE
}
static __device__ __forceinline__ float fast_tanh(float u) {
  return 1.0f - 2.0f / (__expf(2.0f * u) + 1.0f);
}

// ---------------- kernel 0: repack W1,W2 f32 -> bf16, frag-major ----------
// elem idx = m*524288 + kk*8192 + col*16 + hi*8 + e  (col in [0,512), kk kstep)
__global__ void cvt_w(const float* __restrict__ W1, const float* __restrict__ W2,
                      unsigned short* __restrict__ wbf) {
  int gid = blockIdx.x * 256 + threadIdx.x;      // 0..131071 frags of 8
  int hi  = gid & 1;
  int col = (gid >> 1) & 511;
  int kk  = (gid >> 10) & 63;
  int m   = gid >> 16;
  const float* src = (m ? W2 : W1) + col * 1024 + kk * 16 + hi * 8;
  u16x8 v;
  #pragma unroll
  for (int e = 0; e < 8; ++e) v[e] = f2bf(src[e]);
  *(u16x8*)(wbf + (size_t)gid * 8) = v;
}

// ---------------- kernel 1: a[i] = (tanh(xW1^T) * softmax(xW2^T)) @ W3^T ----
// 64 rows/block, 1024 thr, 16 waves = rg(2) x cg(8); wave tile = 32 rows x
// 64 cols x 2 mats (acc 64/thr). One ds_read_b128 A-frag feeds 4 MFMA.
// K in 16 subtiles of 64, dbuf 8KB LDS, x-loads 2 phases deep, W prefetch
// 1 kstep ahead from L2 (frag-major). lgkm-only barriers (vmcnt never drained).
#define ENDBAR() do { \
  asm volatile("s_waitcnt lgkmcnt(0)" ::: "memory"); \
  __builtin_amdgcn_s_barrier(); \
} while (0)

#define MF(A, B, C) __builtin_amdgcn_mfma_f32_32x32x16_bf16((A), (B), (C), 0, 0, 0)

#define KST(BUFOFF, KK, U0, U1, U2, U3, L0, L1, L2, L3) do { \
  L0 = *(const bf16x8*)(wbf + wf0 + (((KK) + 1) << 13)); \
  L1 = *(const bf16x8*)(wbf + wf1 + (((KK) + 1) << 13)); \
  L2 = *(const bf16x8*)(wbf + wf2 + (((KK) + 1) << 13)); \
  L3 = *(const bf16x8*)(wbf + wf3 + (((KK) + 1) << 13)); \
  bf16x8 a_ = *(const bf16x8*)(lds + (BUFOFF) + ((ra0 + (((KK) & 3) << 5)) ^ swz)); \
  __builtin_amdgcn_s_setprio(1); \
  au0 = MF(a_, U0, au0); \
  au1 = MF(a_, U1, au1); \
  av0 = MF(a_, U2, av0); \
  av1 = MF(a_, U3, av1); \
  __builtin_amdgcn_s_setprio(0); \
} while (0)

#define PACK4(DSTBYTE, Q) do { \
  u16x4 _v; _v[0]=f2bf(Q[0]); _v[1]=f2bf(Q[1]); _v[2]=f2bf(Q[2]); _v[3]=f2bf(Q[3]); \
  *(u16x4*)(lds + (DSTBYTE)) = _v; \
} while (0)

__launch_bounds__(1024, 4)
__global__ void alpha_kernel(const float* __restrict__ x,
                             const unsigned short* __restrict__ wbf,
                             const float* __restrict__ W3,
                             float* __restrict__ a_out)
{
  __shared__ unsigned char lds[16384 + 6144];    // 2 x 8KB x-bufs + 6KB reduce
  const int tid  = threadIdx.x;
  const int lane = tid & 63;
  const int wid  = tid >> 6;                     // 0..15
  const int cgi  = wid & 7;                      // col group: 64 cols
  const int rg   = wid >> 3;                     // row group: 32 rows
  const int l31  = lane & 31;
  const int hi   = lane >> 5;
  const int row0 = blockIdx.x << 6;

  // staging: subtile = 64 rows x 64 k (bf16, 8KB). thread -> row sr, 4-float chunk sc
  const int sr = tid >> 4;                       // 0..63
  const int sc = tid & 15;                       // 0..15
  const float* xptr = x + ((size_t)(row0 + sr) << 10) + (sc << 2);
  const uint32_t wbyte = ((uint32_t)((sr << 7) + (sc << 3))) ^ (((uint32_t)(sr & 7)) << 4);

  // W frag element-offsets (frag-major layout): frag c cols = cgi*64 + c*32 + l31
  const int c0 = (cgi << 6) + l31;
  const int c1 = c0 + 32;
  const uint32_t wf0 = (uint32_t)((c0 << 4) + (hi << 3));            // W1 frag0
  const uint32_t wf1 = (uint32_t)((c1 << 4) + (hi << 3));            // W1 frag1
  const uint32_t wf2 = wf0 + 524288u;                                 // W2 frag0
  const uint32_t wf3 = wf1 + 524288u;                                 // W2 frag1

  f32x16 au0, au1, av0, av1;
  #pragma unroll
  for (int i = 0; i < 16; ++i) { au0[i]=0.f; au1[i]=0.f; av0[i]=0.f; av1[i]=0.f; }

  const uint32_t swz = (((uint32_t)(l31 & 7)) << 4);
  const uint32_t ra0 = (((uint32_t)rg) << 12) + (((uint32_t)l31) << 7) + (((uint32_t)hi) << 4);

  // prologue: sub0 -> buf0; sub1 -> regs; W kstep0 -> WA*
  f32x4 xa = *(const f32x4*)xptr;
  f32x4 xb = *(const f32x4*)(xptr + 64);
  PACK4(wbyte, xa);
  bf16x8 WA0 = *(const bf16x8*)(wbf + wf0);
  bf16x8 WA1 = *(const bf16x8*)(wbf + wf1);
  bf16x8 WA2 = *(const bf16x8*)(wbf + wf2);
  bf16x8 WA3 = *(const bf16x8*)(wbf + wf3);
  bf16x8 WB0, WB1, WB2, WB3;
  ENDBAR();

  #pragma unroll 1
  for (int t = 0; t < 16; t += 2) {
    // even phase: compute buf0 (sub t); pack sub t+1 -> buf1; load sub t+2 -> xa
    if (t + 2 < 16) xa = *(const f32x4*)(xptr + ((t + 2) << 6));
    PACK4(8192 + wbyte, xb);
    KST(0, t * 4 + 0, WA0, WA1, WA2, WA3, WB0, WB1, WB2, WB3);
    KST(0, t * 4 + 1, WB0, WB1, WB2, WB3, WA0, WA1, WA2, WA3);
    KST(0, t * 4 + 2, WA0, WA1, WA2, WA3, WB0, WB1, WB2, WB3);
    KST(0, t * 4 + 3, WB0, WB1, WB2, WB3, WA0, WA1, WA2, WA3);
    ENDBAR();
    // odd phase: compute buf1 (sub t+1); pack sub t+2 -> buf0; load sub t+3 -> xb
    if (t + 3 < 16) xb = *(const f32x4*)(xptr + ((t + 3) << 6));
    if (t + 2 < 16) PACK4(wbyte, xa);
    KST(8192, t * 4 + 4, WA0, WA1, WA2, WA3, WB0, WB1, WB2, WB3);
    KST(8192, t * 4 + 5, WB0, WB1, WB2, WB3, WA0, WA1, WA2, WA3);
    KST(8192, t * 4 + 6, WA0, WA1, WA2, WA3, WB0, WB1, WB2, WB3);
    KST(8192, t * 4 + 7, WB0, WB1, WB2, WB3, WA0, WA1, WA2, WA3);
    ENDBAR();
  }

  // ---- epilogue ----
  // C/D map (m74/m101): col = lane&31 (within 32-col tile),
  // row = (reg&3) + 8*(reg>>2) + 4*(lane>>5); wave rows = rg*32 + row.
  float w3a = W3[c0];
  float w3b = W3[c1];
  float* redm = (float*)(lds + 16384);           // [8 cg][64 rows]
  float* reds = redm + 512;
  float* redn = redm + 1024;

  {
    float m_[16], s_[16], n_[16];
    #pragma unroll
    for (int r = 0; r < 16; ++r) m_[r] = fmaxf(av0[r], av1[r]);
    #pragma unroll
    for (int d = 1; d < 32; d <<= 1)
      #pragma unroll
      for (int r = 0; r < 16; ++r) m_[r] = fmaxf(m_[r], __shfl_xor(m_[r], d));
    #pragma unroll
    for (int r = 0; r < 16; ++r) {
      float p0 = __expf(av0[r] - m_[r]);
      float p1 = __expf(av1[r] - m_[r]);
      s_[r] = p0 + p1;
      n_[r] = fast_tanh(au0[r]) * p0 * w3a + fast_tanh(au1[r]) * p1 * w3b;
    }
    #pragma unroll
    for (int d = 1; d < 32; d <<= 1)
      #pragma unroll
      for (int r = 0; r < 16; ++r) { s_[r] += __shfl_xor(s_[r], d); n_[r] += __shfl_xor(n_[r], d); }
    if (l31 == 0) {
      #pragma unroll
      for (int r = 0; r < 16; ++r) {
        int row = (rg << 5) + (r & 3) + ((r >> 2) << 3) + (hi << 2);
        redm[(cgi << 6) + row] = m_[r];
        reds[(cgi << 6) + row] = s_[r];
        redn[(cgi << 6) + row] = n_[r];
      }
    }
  }
  __syncthreads();
  if (tid < 64) {
    float m = redm[tid];
    #pragma unroll
    for (int c = 1; c < 8; ++c) m = fmaxf(m, redm[(c << 6) + tid]);
    float s = 0.f, n = 0.f;
    #pragma unroll
    for (int c = 0; c < 8; ++c) {
      float sc2 = __expf(redm[(c << 6) + tid] - m);
      s += reds[(c << 6) + tid] * sc2;
      n += redn[(c << 6) + tid] * sc2;
    }
    a_out[row0 + tid] = n / s;
  }
}

// ---------------- kernel 2: segment softmax weights ----------------
static __device__ __forceinline__ int lower_bound(const int* __restrict__ batch, int key) {
  int lo = 0, hi = N_ROWS;
  while (lo < hi) { int mid = (lo + hi) >> 1; if (batch[mid] < key) lo = mid + 1; else hi = mid; }
  return lo;
}

__global__ void seg_kernel(const float* __restrict__ a, const int* __restrict__ batch,
                           float* __restrict__ w) {
  __shared__ float sm[8];
  int b = blockIdx.x;
  int start = lower_bound(batch, b);
  int end   = lower_bound(batch, b + 1);
  int tid = threadIdx.x;

  float m = -3.4e38f;
  for (int i = start + tid; i < end; i += 256) m = fmaxf(m, a[i]);
  for (int d = 1; d < 64; d <<= 1) m = fmaxf(m, __shfl_xor(m, d));
  if ((tid & 63) == 0) sm[tid >> 6] = m;
  __syncthreads();
  m = fmaxf(fmaxf(sm[0], sm[1]), fmaxf(sm[2], sm[3]));

  float s = 0.f;
  for (int i = start + tid; i < end; i += 256) s += __expf(a[i] - m);
  for (int d = 1; d < 64; d <<= 1) s += __shfl_xor(s, d);
  if ((tid & 63) == 0) sm[4 + (tid >> 6)] = s;
  __syncthreads();
  s = sm[4] + sm[5] + sm[6] + sm[7];

  float rinv = 1.0f / s;
  for (int i = start + tid; i < end; i += 256) w[i] = __expf(a[i] - m) * rinv;
}

// ---------------- kernel 3: z[b] = sum_i w_i * x_i ----------------
__global__ void z_kernel(const float* __restrict__ x, const float* __restrict__ w,
                         const int* __restrict__ batch, float* __restrict__ z) {
  int b = blockIdx.x >> 2, part = blockIdx.x & 3;
  int start = lower_bound(batch, b);
  int end   = lower_bound(batch, b + 1);
  int len = end - start;
  int ps = start + ((len * part) >> 2);
  int pe = start + ((len * (part + 1)) >> 2);
  int col = threadIdx.x << 2;

  f32x4 acc = (f32x4){0.f, 0.f, 0.f, 0.f};
  for (int i = ps; i < pe; ++i) {
    f32x4 xv = *(const f32x4*)(x + ((size_t)i << 10) + col);
    float wi = w[i];
    acc += xv * wi;
  }
  float* zp = z + ((size_t)b << 10) + col;
  atomicAdd(zp + 0, acc[0]);
  atomicAdd(zp + 1, acc[1]);
  atomicAdd(zp + 2, acc[2]);
  atomicAdd(zp + 3, acc[3]);
}

// ---------------- launch ----------------
extern "C" void kernel_launch(void* const* d_in, const int* in_sizes, int n_in,
                              void* d_out, int out_size, void* d_ws, size_t ws_size,
                              hipStream_t stream) {
  const float* x     = (const float*)d_in[0];
  const int*   batch = (const int*)d_in[1];
  const float* W1    = (const float*)d_in[2];
  const float* W2    = (const float*)d_in[3];
  const float* W3    = (const float*)d_in[4];
  float* z = (float*)d_out;

  // ws layout: [0,2MB) W1|W2 bf16 frag-major ; [2MB,3MB) a[N] f32 ; [3MB,4MB) w[N] f32
  unsigned short* wbf = (unsigned short*)d_ws;
  float* a = (float*)((char*)d_ws + (2u << 20));
  float* w = (float*)((char*)d_ws + (3u << 20));

  (void)hipMemsetAsync(d_out, 0, (size_t)N_SEG * D_DIM * sizeof(float), stream);

  cvt_w<<<512, 256, 0, stream>>>(W1, W2, wbf);

  alpha_kernel<<<N_ROWS / 64, 1024, 0, stream>>>(x, wbf, W3, a);

  seg_kernel<<<N_SEG, 256, 0, stream>>>(a, batch, w);

  z_kernel<<<N_SEG * 4, 256, 0, stream>>>(x, w, batch, z);
}